// Round 1
// baseline (14087.227 us; speedup 1.0000x reference)
//
#include <hip/hip_runtime.h>
#include <math.h>

// ---- problem constants ----
#define BB 64
#define SS 512
#define II 1024
#define HH 1024

typedef _Float16 half8  __attribute__((ext_vector_type(8)));
typedef _Float16 half4_t __attribute__((ext_vector_type(4)));
typedef float    float4_t __attribute__((ext_vector_type(4)));

// ---- workspace layout (bytes) ----
#define XH_OFF   0u            // fp16 x, (S,B,I) layout: 67108864 B
#define WIH_OFF  67108864u     // fp16 W_ih [H][I]: 2097152 B
#define WHH_OFF  69206016u     // fp16 W_hh [H][H]: 2097152 B
#define HBUF_OFF 71303168u     // fp16 h double buffer [2][64][1024]: 262144 B
#define CNT_OFF  71565312u     // 8 group counters
// total needed: ~71.6 MB of ws

__device__ __forceinline__ void load_lds16(const void* g, void* l) {
  __builtin_amdgcn_global_load_lds(
      (const __attribute__((address_space(1))) void*)g,
      (__attribute__((address_space(3))) void*)l, 16, 0, 0);
}

// ============================================================
// Kernel 0: convert x -> fp16 time-major, weights -> fp16, zero counters
// ============================================================
__global__ __launch_bounds__(256) void convert_kernel(
    const float* __restrict__ x, const float* __restrict__ Wih,
    const float* __restrict__ Whh, _Float16* __restrict__ xh,
    _Float16* __restrict__ Wihh, _Float16* __restrict__ Whhh,
    unsigned* __restrict__ cnt) {
  long tid = (long)blockIdx.x * blockDim.x + threadIdx.x;
  if (tid < 8) cnt[tid] = 0;
  if (tid < 8388608L) {  // x: 33554432 floats = 8388608 float4
    long f = tid;
    int i4 = (int)(f & 255);          // float4 index within I row
    int s  = (int)((f >> 8) & 511);
    int b  = (int)(f >> 17);
    float4_t v = ((const float4_t*)x)[f];
    half4_t h;
    h[0] = (_Float16)v[0]; h[1] = (_Float16)v[1];
    h[2] = (_Float16)v[2]; h[3] = (_Float16)v[3];
    long dst = ((long)(s * 64 + b) * 1024 + i4 * 4) >> 2;  // half4 units
    ((half4_t*)xh)[dst] = h;
  } else if (tid < 8388608L + 262144L) {
    long f = tid - 8388608L;
    float4_t v = ((const float4_t*)Wih)[f];
    half4_t h;
    h[0] = (_Float16)v[0]; h[1] = (_Float16)v[1];
    h[2] = (_Float16)v[2]; h[3] = (_Float16)v[3];
    ((half4_t*)Wihh)[f] = h;
  } else if (tid < 8388608L + 524288L) {
    long f = tid - 8388608L - 262144L;
    float4_t v = ((const float4_t*)Whh)[f];
    half4_t h;
    h[0] = (_Float16)v[0]; h[1] = (_Float16)v[1];
    h[2] = (_Float16)v[2]; h[3] = (_Float16)v[3];
    ((half4_t*)Whhh)[f] = h;
  }
}

// ============================================================
// Kernel 1: xi = x_h @ W_ih^T + b_ih  (fp16 MFMA, fp32 out -> d_out rows s*B+b)
// A: [32768][1024] fp16 (time-major rows), B: [1024][1024] fp16 (K-major)
// 128x128 tile, BK=32, 4 waves in 2x2, 4x4 16x16x32 tiles per wave.
// ============================================================
__global__ __launch_bounds__(256) void gemm_xi(
    const _Float16* __restrict__ Ap, const _Float16* __restrict__ Bp,
    const float* __restrict__ bias, float* __restrict__ out) {
  __shared__ _Float16 Al[128 * 32];
  __shared__ _Float16 Bl[128 * 32];
  int bid = blockIdx.x;
  int nT = bid & 7, mT = bid >> 3;
  int tid = threadIdx.x;
  int lane = tid & 63, wv = tid >> 6;
  int wm = wv & 1, wn = wv >> 1;
  int nl = lane & 15, quad = lane >> 4;
  long mBase = (long)mT * 128;
  long nBase = (long)nT * 128;
  float4_t acc[4][4] = {};

  for (int k0 = 0; k0 < 1024; k0 += 32) {
    __syncthreads();  // previous iter's LDS readers done
#pragma unroll
    for (int c2 = 0; c2 < 2; ++c2) {
      int c = wv * 2 + c2;            // chunk 0..7, 1KB each
      int flat = c * 64 + lane;       // 16B unit id (512 per tile)
      int row = flat >> 2;
      int off = (flat & 3) * 8;       // halves
      load_lds16(Ap + (mBase + row) * 1024 + k0 + off, &Al[c * 512]);
      load_lds16(Bp + (nBase + row) * 1024 + k0 + off, &Bl[c * 512]);
    }
    __syncthreads();  // vmcnt(0) drained before barrier (compiler-emitted)
    half8 af[4], bf[4];
#pragma unroll
    for (int t = 0; t < 4; ++t) {
      af[t] = *(const half8*)&Al[(wm * 64 + t * 16 + nl) * 32 + quad * 8];
      bf[t] = *(const half8*)&Bl[(wn * 64 + t * 16 + nl) * 32 + quad * 8];
    }
#pragma unroll
    for (int tm = 0; tm < 4; ++tm)
#pragma unroll
      for (int tn = 0; tn < 4; ++tn)
        acc[tm][tn] = __builtin_amdgcn_mfma_f32_16x16x32_f16(
            af[tm], bf[tn], acc[tm][tn], 0, 0, 0);
  }
  // epilogue: D[m][n]: row m = quad*4+r, col n = nl
#pragma unroll
  for (int tm = 0; tm < 4; ++tm) {
    long rowg = mBase + wm * 64 + tm * 16 + quad * 4;
#pragma unroll
    for (int tn = 0; tn < 4; ++tn) {
      long colg = nBase + wn * 64 + tn * 16 + nl;
      float bi = bias[colg];
#pragma unroll
      for (int r = 0; r < 4; ++r)
        out[(rowg + r) * 1024 + colg] = acc[tm][tn][r] + bi;
    }
  }
}

// ============================================================
// Kernel 2: persistent recurrence.
// 256 WGs x 128 thr. group g = bid&7 (8 batches b0=8g), slice = bid>>3
// WG rows r0 = slice*32; wave wv owns 16 rows in its private 32KB LDS half.
// Per step: MFMA (M=8 batches in 16 slots) x (N=16 rows) x K=1024,
// h fragments gathered from global double buffer; release/acquire counter sync.
// ============================================================
__global__ __launch_bounds__(128) void rnn_rec(
    const _Float16* __restrict__ Whh, const float* __restrict__ bhh,
    float* __restrict__ out, _Float16* __restrict__ hbuf,
    unsigned* __restrict__ cnt) {
  __shared__ _Float16 Wl[2][16 * 1024];  // 64 KB, wave-private halves
  int bid = blockIdx.x;
  int g = bid & 7;
  int slice = bid >> 3;
  int r0 = slice * 32;
  int b0 = g * 8;
  int tid = threadIdx.x;
  int wv = tid >> 6;
  int lane = tid & 63;
  int nl = lane & 15, quad = lane >> 4;
  int myrow0 = r0 + wv * 16;

  // preload this wave's 16 W_hh rows, XOR-swizzled (k8 ^= n&7) for bank spread
#pragma unroll 4
  for (int it = 0; it < 32; ++it) {
    int c = it * 64 + lane;        // 2048 chunks of 8 halves
    int n = c >> 7, k8 = c & 127;
    half8 v = *(const half8*)(Whh + (long)(myrow0 + n) * 1024 + k8 * 8);
    int sk8 = k8 ^ (n & 7);
    *(half8*)&Wl[wv][n * 1024 + sk8 * 8] = v;
  }

  int mb = nl & 7;  // batch row for A fragment (lanes 8..15 duplicate)
  volatile unsigned* cg = nullptr;  (void)cg;

#pragma unroll 1
  for (int s = 0; s < 512; ++s) {
    float4_t acc0 = {0.f, 0.f, 0.f, 0.f}, acc1 = {0.f, 0.f, 0.f, 0.f};
    if (s > 0) {
      unsigned target = (unsigned)(32 * s);
      while (__hip_atomic_load(&cnt[g], __ATOMIC_ACQUIRE,
                               __HIP_MEMORY_SCOPE_AGENT) < target)
        __builtin_amdgcn_s_sleep(1);
      __threadfence();
      const _Float16* hsrc = hbuf + ((s - 1) & 1) * 65536 + b0 * 1024;
#pragma unroll
      for (int kt = 0; kt < 32; kt += 2) {
        half8 a0 = *(const half8*)(hsrc + mb * 1024 + kt * 32 + quad * 8);
        half8 b0f = *(const half8*)&Wl[wv][nl * 1024 +
                     (((kt * 4) + quad) ^ (nl & 7)) * 8];
        acc0 = __builtin_amdgcn_mfma_f32_16x16x32_f16(a0, b0f, acc0, 0, 0, 0);
        half8 a1 = *(const half8*)(hsrc + mb * 1024 + (kt + 1) * 32 + quad * 8);
        half8 b1f = *(const half8*)&Wl[wv][nl * 1024 +
                     ((((kt + 1) * 4) + quad) ^ (nl & 7)) * 8];
        acc1 = __builtin_amdgcn_mfma_f32_16x16x32_f16(a1, b1f, acc1, 0, 0, 0);
      }
    }
    float4_t D = acc0 + acc1;
    int col = myrow0 + nl;
    if (quad < 2) {
      float bi = bhh[col];
#pragma unroll
      for (int r = 0; r < 4; ++r) {
        int mbat = quad * 4 + r;  // batch 0..7
        long oidx = ((long)s * 64 + b0 + mbat) * 1024 + col;
        float pre = D[r] + out[oidx] + bi;   // xi already includes b_ih
        float hv = tanhf(pre);
        out[oidx] = hv;
        hbuf[(s & 1) * 65536 + (b0 + mbat) * 1024 + col] = (_Float16)hv;
        if (s == 511)
          out[33554432L + (b0 + mbat) * 1024 + col] = hv;  // h_final tail
      }
    }
    __syncthreads();  // both waves' stores drained (vmcnt(0) before barrier)
    if (tid == 0)
      __hip_atomic_fetch_add(&cnt[g], 1u, __ATOMIC_RELEASE,
                             __HIP_MEMORY_SCOPE_AGENT);
  }
}

// ============================================================
extern "C" void kernel_launch(void* const* d_in, const int* in_sizes, int n_in,
                              void* d_out, int out_size, void* d_ws,
                              size_t ws_size, hipStream_t stream) {
  const float* x   = (const float*)d_in[0];
  const float* Wih = (const float*)d_in[1];
  const float* bih = (const float*)d_in[2];
  const float* Whh = (const float*)d_in[3];
  const float* bhh = (const float*)d_in[4];
  char* ws = (char*)d_ws;
  _Float16* xh   = (_Float16*)(ws + XH_OFF);
  _Float16* Wihh = (_Float16*)(ws + WIH_OFF);
  _Float16* Whhh = (_Float16*)(ws + WHH_OFF);
  _Float16* hbuf = (_Float16*)(ws + HBUF_OFF);
  unsigned* cnt  = (unsigned*)(ws + CNT_OFF);
  float* out = (float*)d_out;

  convert_kernel<<<34816, 256, 0, stream>>>(x, Wih, Whh, xh, Wihh, Whhh, cnt);
  gemm_xi<<<2048, 256, 0, stream>>>(xh, Wihh, bih, out);
  rnn_rec<<<256, 128, 0, stream>>>(Whhh, bhh, out, hbuf, cnt);
}

// Round 3
// 5775.145 us; speedup vs baseline: 2.4393x; 2.4393x over previous
//
#include <hip/hip_runtime.h>
#include <math.h>

// ---- problem constants ----
#define BB 64
#define SS 512
#define II 1024
#define HH 1024

typedef _Float16 half8  __attribute__((ext_vector_type(8)));
typedef _Float16 half4_t __attribute__((ext_vector_type(4)));
typedef float    float4_t __attribute__((ext_vector_type(4)));

// ---- workspace layout (bytes) ----
#define XH_OFF   0u            // fp16 x, (S,B,I) layout: 67108864 B
#define WIH_OFF  67108864u     // fp16 W_ih [H][I]: 2097152 B
#define WHH_OFF  69206016u     // fp16 W_hh [H][H]: 2097152 B
#define HBUF_OFF 71303168u     // fp16 h double buffer [2][64][1024]: 262144 B
#define FLG_OFF  71565312u     // 32 per-WG flags, padded to 128 B stride (4 KB)

__device__ __forceinline__ void load_lds16(const void* g, void* l) {
  __builtin_amdgcn_global_load_lds(
      (const __attribute__((address_space(1))) void*)g,
      (__attribute__((address_space(3))) void*)l, 16, 0, 0);
}

// ============================================================
// Kernel 0: convert x -> fp16 time-major, weights -> fp16, zero flags
// ============================================================
__global__ __launch_bounds__(256) void convert_kernel(
    const float* __restrict__ x, const float* __restrict__ Wih,
    const float* __restrict__ Whh, _Float16* __restrict__ xh,
    _Float16* __restrict__ Wihh, _Float16* __restrict__ Whhh,
    unsigned* __restrict__ flg) {
  long tid = (long)blockIdx.x * blockDim.x + threadIdx.x;
  if (tid < 1024) flg[tid] = 0;
  if (tid < 8388608L) {  // x: 33554432 floats = 8388608 float4
    long f = tid;
    int i4 = (int)(f & 255);          // float4 index within I row
    int s  = (int)((f >> 8) & 511);
    int b  = (int)(f >> 17);
    float4_t v = ((const float4_t*)x)[f];
    half4_t h;
    h[0] = (_Float16)v[0]; h[1] = (_Float16)v[1];
    h[2] = (_Float16)v[2]; h[3] = (_Float16)v[3];
    long dst = ((long)(s * 64 + b) * 1024 + i4 * 4) >> 2;  // half4 units
    ((half4_t*)xh)[dst] = h;
  } else if (tid < 8388608L + 262144L) {
    long f = tid - 8388608L;
    float4_t v = ((const float4_t*)Wih)[f];
    half4_t h;
    h[0] = (_Float16)v[0]; h[1] = (_Float16)v[1];
    h[2] = (_Float16)v[2]; h[3] = (_Float16)v[3];
    ((half4_t*)Wihh)[f] = h;
  } else if (tid < 8388608L + 524288L) {
    long f = tid - 8388608L - 262144L;
    float4_t v = ((const float4_t*)Whh)[f];
    half4_t h;
    h[0] = (_Float16)v[0]; h[1] = (_Float16)v[1];
    h[2] = (_Float16)v[2]; h[3] = (_Float16)v[3];
    ((half4_t*)Whhh)[f] = h;
  }
}

// ============================================================
// Kernel 1: xi = x_h @ W_ih^T + b_ih  (fp16 MFMA, fp32 out -> d_out rows s*B+b)
// ============================================================
__global__ __launch_bounds__(256) void gemm_xi(
    const _Float16* __restrict__ Ap, const _Float16* __restrict__ Bp,
    const float* __restrict__ bias, float* __restrict__ out) {
  __shared__ _Float16 Al[128 * 32];
  __shared__ _Float16 Bl[128 * 32];
  int bid = blockIdx.x;
  int nT = bid & 7, mT = bid >> 3;
  int tid = threadIdx.x;
  int lane = tid & 63, wv = tid >> 6;
  int wm = wv & 1, wn = wv >> 1;
  int nl = lane & 15, quad = lane >> 4;
  long mBase = (long)mT * 128;
  long nBase = (long)nT * 128;
  float4_t acc[4][4] = {};

  for (int k0 = 0; k0 < 1024; k0 += 32) {
    __syncthreads();
#pragma unroll
    for (int c2 = 0; c2 < 2; ++c2) {
      int c = wv * 2 + c2;
      int flat = c * 64 + lane;
      int row = flat >> 2;
      int off = (flat & 3) * 8;
      load_lds16(Ap + (mBase + row) * 1024 + k0 + off, &Al[c * 512]);
      load_lds16(Bp + (nBase + row) * 1024 + k0 + off, &Bl[c * 512]);
    }
    __syncthreads();
    half8 af[4], bf[4];
#pragma unroll
    for (int t = 0; t < 4; ++t) {
      af[t] = *(const half8*)&Al[(wm * 64 + t * 16 + nl) * 32 + quad * 8];
      bf[t] = *(const half8*)&Bl[(wn * 64 + t * 16 + nl) * 32 + quad * 8];
    }
#pragma unroll
    for (int tm = 0; tm < 4; ++tm)
#pragma unroll
      for (int tn = 0; tn < 4; ++tn)
        acc[tm][tn] = __builtin_amdgcn_mfma_f32_16x16x32_f16(
            af[tm], bf[tn], acc[tm][tn], 0, 0, 0);
  }
#pragma unroll
  for (int tm = 0; tm < 4; ++tm) {
    long rowg = mBase + wm * 64 + tm * 16 + quad * 4;
#pragma unroll
    for (int tn = 0; tn < 4; ++tn) {
      long colg = nBase + wn * 64 + tn * 16 + nl;
      float bi = bias[colg];
#pragma unroll
      for (int r = 0; r < 4; ++r)
        out[(rowg + r) * 1024 + colg] = acc[tm][tn][r] + bi;
    }
  }
}

// ============================================================
// Kernel 2: persistent recurrence — ONE group of 32 WGs x 256 thr.
// WG `slice` owns output cols [slice*32, slice*32+32), full M=64 batches.
// W_hh rows for those cols live in 64 KB LDS (XOR-swizzled).
// 4 waves: wm = wv&1 -> batch half (32), wn = wv>>1 -> col group (16).
// Sync: per-WG padded flag, RELEASE store by tid0 after __syncthreads;
// consumers poll all 32 flags RELAXED in parallel lanes + one ACQUIRE fence.
// ============================================================
__global__ __launch_bounds__(256) void rnn_rec(
    const _Float16* __restrict__ Whh, const float* __restrict__ bhh,
    float* __restrict__ out, _Float16* __restrict__ hbuf,
    unsigned* __restrict__ flags) {
  __shared__ _Float16 Wl[32 * 1024];  // 64 KB
  const int slice = blockIdx.x;       // 0..31
  const int tid = threadIdx.x;
  const int wv = tid >> 6, lane = tid & 63;
  const int wm = wv & 1, wn = wv >> 1;
  const int nl = lane & 15, quad = lane >> 4;
  const int colbase = slice * 32;

  // preload W_hh rows [colbase, colbase+32), swizzle k8 ^= (n&7) (2-way banks = free)
#pragma unroll 4
  for (int it = 0; it < 32; ++it) {
    int c = it * 256 + tid;          // 8192 half8 chunks
    int n = c >> 7, k8 = c & 127;
    half8 v = *(const half8*)(Whh + (long)(colbase + n) * 1024 + k8 * 8);
    *(half8*)&Wl[n * 1024 + (k8 ^ (n & 7)) * 8] = v;
  }
  __syncthreads();

  const int mycol = colbase + wn * 16 + nl;
  const float bi = bhh[mycol];
  const int swz = (nl & 7);

#pragma unroll 1
  for (int s = 0; s < 512; ++s) {
    // ---- xi prefetch: independent of h, in flight during the poll ----
    float xi[2][4];
#pragma unroll
    for (int t = 0; t < 2; ++t)
#pragma unroll
      for (int r = 0; r < 4; ++r) {
        int bat = wm * 32 + t * 16 + quad * 4 + r;
        xi[t][r] = out[((long)s * 64 + bat) * 1024 + mycol];
      }

    float4_t acc0 = {0.f, 0.f, 0.f, 0.f}, acc1 = {0.f, 0.f, 0.f, 0.f};
    if (s > 0) {
      if (wv == 0) {
        const unsigned fidx = (unsigned)(lane & 31) << 5;  // 128-B stride
        while (true) {
          unsigned f = __hip_atomic_load(&flags[fidx], __ATOMIC_RELAXED,
                                         __HIP_MEMORY_SCOPE_AGENT);
          if (__ballot(f < (unsigned)s) == 0ull) break;
          __builtin_amdgcn_s_sleep(2);
        }
      }
      __syncthreads();
      __builtin_amdgcn_fence(__ATOMIC_ACQUIRE, "agent");
      const _Float16* hsrc = hbuf + ((s - 1) & 1) * 65536;
#pragma unroll 8
      for (int kt = 0; kt < 32; ++kt) {
        half8 bfr = *(const half8*)&Wl[(wn * 16 + nl) * 1024 +
                                       ((kt * 4 + quad) ^ swz) * 8];
        half8 a0 = *(const half8*)(hsrc + (wm * 32 + nl) * 1024 +
                                   kt * 32 + quad * 8);
        half8 a1 = *(const half8*)(hsrc + (wm * 32 + 16 + nl) * 1024 +
                                   kt * 32 + quad * 8);
        acc0 = __builtin_amdgcn_mfma_f32_16x16x32_f16(a0, bfr, acc0, 0, 0, 0);
        acc1 = __builtin_amdgcn_mfma_f32_16x16x32_f16(a1, bfr, acc1, 0, 0, 0);
      }
    }

    // ---- epilogue: h = tanh(xi + h@Whh^T + bhh); publish hbuf, then flag ----
    float hv[2][4];
#pragma unroll
    for (int t = 0; t < 2; ++t)
#pragma unroll
      for (int r = 0; r < 4; ++r) {
        int bat = wm * 32 + t * 16 + quad * 4 + r;
        float pre = (t == 0 ? acc0[r] : acc1[r]) + xi[t][r] + bi;
        float e = __expf(2.f * pre);
        float v = 1.f - 2.f / (e + 1.f);
        hv[t][r] = v;
        hbuf[(s & 1) * 65536 + bat * 1024 + mycol] = (_Float16)v;
      }
    __syncthreads();  // drains all waves' hbuf stores (vmcnt(0) before barrier)
    if (tid == 0)
      __hip_atomic_store(&flags[(unsigned)slice << 5], (unsigned)(s + 1),
                         __ATOMIC_RELEASE, __HIP_MEMORY_SCOPE_AGENT);
    // out stores off the critical path (not part of the sync protocol)
#pragma unroll
    for (int t = 0; t < 2; ++t)
#pragma unroll
      for (int r = 0; r < 4; ++r) {
        int bat = wm * 32 + t * 16 + quad * 4 + r;
        out[((long)s * 64 + bat) * 1024 + mycol] = hv[t][r];
        if (s == 511)
          out[33554432L + bat * 1024 + mycol] = hv[t][r];
      }
  }
}

// ============================================================
extern "C" void kernel_launch(void* const* d_in, const int* in_sizes, int n_in,
                              void* d_out, int out_size, void* d_ws,
                              size_t ws_size, hipStream_t stream) {
  const float* x   = (const float*)d_in[0];
  const float* Wih = (const float*)d_in[1];
  const float* bih = (const float*)d_in[2];
  const float* Whh = (const float*)d_in[3];
  const float* bhh = (const float*)d_in[4];
  char* ws = (char*)d_ws;
  _Float16* xh   = (_Float16*)(ws + XH_OFF);
  _Float16* Wihh = (_Float16*)(ws + WIH_OFF);
  _Float16* Whhh = (_Float16*)(ws + WHH_OFF);
  _Float16* hbuf = (_Float16*)(ws + HBUF_OFF);
  unsigned* flg  = (unsigned*)(ws + FLG_OFF);
  float* out = (float*)d_out;

  convert_kernel<<<34816, 256, 0, stream>>>(x, Wih, Whh, xh, Wihh, Whhh, flg);
  gemm_xi<<<2048, 256, 0, stream>>>(xh, Wihh, bih, out);
  rnn_rec<<<32, 256, 0, stream>>>(Whhh, bhh, out, hbuf, flg);
}